// Round 6
// baseline (94.315 us; speedup 1.0000x reference)
//
#include <hip/hip_runtime.h>
#include <hip/hip_bf16.h>
#include <stdint.h>

typedef _Float16 half8 __attribute__((ext_vector_type(8)));
typedef _Float16 half4 __attribute__((ext_vector_type(4)));
typedef float f32x4 __attribute__((ext_vector_type(4)));
typedef unsigned long long u64;

#define N_ROWS 4096
#define DIM 1024
#define KCLS 32
#define MARGIN_F 0.3f
#define SENTN 0xFFFFFFFFFFFFFFFFull

// ---------------- global -> LDS direct staging (16B per lane) ----------------
typedef const __attribute__((address_space(1))) void GASV;
typedef __attribute__((address_space(3))) void LASV;

__device__ __forceinline__ void gload_lds16(const void* g, void* l) {
    __builtin_amdgcn_global_load_lds((GASV*)g, (LASV*)l, 16, 0, 0);
}

// ---------------- prep: sq, f16 convert, prediction argmax ----------------
__global__ __launch_bounds__(256) void prep_kernel(
    const float* __restrict__ inputs, const float* __restrict__ prediction,
    _Float16* __restrict__ xh, float* __restrict__ sq, int* __restrict__ pred_cls)
{
    int wid = threadIdx.x >> 6, lane = threadIdx.x & 63;
    int r = blockIdx.x * 4 + wid;
    const float* row = inputs + (size_t)r * DIM;
    _Float16* hrow = xh + (size_t)r * DIM;
    float s = 0.f;
#pragma unroll
    for (int c = 0; c < 4; ++c) {
        int idx = lane * 4 + c * 256;
        float4 v = *(const float4*)(row + idx);
        s += v.x * v.x + v.y * v.y + v.z * v.z + v.w * v.w;
        half4 h;
        h.x = (_Float16)v.x; h.y = (_Float16)v.y;
        h.z = (_Float16)v.z; h.w = (_Float16)v.w;
        *(half4*)(hrow + idx) = h;
    }
#pragma unroll
    for (int off = 32; off; off >>= 1) s += __shfl_xor(s, off);

    u64 key = 0ull;
    if (lane < KCLS) {
        unsigned b = __float_as_uint(prediction[(size_t)r * KCLS + lane]);
        unsigned u = (b & 0x80000000u) ? ~b : (b | 0x80000000u);
        key = ((u64)u << 32) | (unsigned)(KCLS - 1 - lane);
    }
#pragma unroll
    for (int off = 32; off; off >>= 1) {
        u64 o = __shfl_xor(key, off);
        if (o > key) key = o;
    }
    if (lane == 0) {
        sq[r] = s;
        pred_cls[r] = KCLS - 1 - (int)(key & 0xFFFFFFFFu);
    }
}

// ---------------- f16 MFMA GEMM -> d^2 matrix, symmetric-triangle mode ----------------
// mode 0: grid 528 blocks = upper block-triangle (bx<=by); off-diag blocks also
//         write the mirrored tile (float4 along q = 4 consecutive rows).
// mode 1: rectangular chunk fallback (rows rb0+..., all cols), no mirror.
// Output element = clamp(sq[i]+sq[j]-2*dot, 1e-12) -- select consumes it directly.
__global__ __launch_bounds__(256) void gemm_kernel(
    const _Float16* __restrict__ X, const float* __restrict__ sq,
    float* __restrict__ out, int mode, int rb0)
{
    __shared__ __align__(16) _Float16 As[128 * 64];
    __shared__ __align__(16) _Float16 Bs[128 * 64];
    int tid = threadIdx.x;

    int bx, by;
    bool diag = false, mirror = false;
    if (mode == 0) {
        // bijective XCD swizzle over 528 blocks (528 = 8*66)
        int u = (blockIdx.x & 7) * 66 + (blockIdx.x >> 3);
        int t_ = (int)((sqrtf(8.f * u + 1.f) - 1.f) * 0.5f);
        while ((t_ + 1) * (t_ + 2) / 2 <= u) ++t_;
        while (t_ * (t_ + 1) / 2 > u) --t_;
        by = t_;
        bx = u - t_ * (t_ + 1) / 2;
        diag = (bx == by);
        mirror = !diag;
    } else {
        int nwg = gridDim.x;                 // multiple of 32 -> %8==0
        int q = nwg >> 3;
        int swz = ((int)blockIdx.x & 7) * q + ((int)blockIdx.x >> 3);
        int nbx = nwg / 32;
        bx = swz % nbx;
        by = swz / nbx;
    }

    // staging: thread t stages LDS row (p*32 + (t>>3)), slot (t&7);
    // source carries the inverse XOR swizzle.
    int rs = tid >> 3;
    int ss = tid & 7;
    int srcslot = ss ^ (rs & 7);
    const _Float16* gA = X + (size_t)(rb0 + bx * 128 + rs) * DIM + srcslot * 8;
    const _Float16* gB = X + (size_t)(by * 128 + rs) * DIM + srcslot * 8;
    _Float16* lA = As + tid * 8;
    _Float16* lB = Bs + tid * 8;

    int wid = tid >> 6, lane = tid & 63;
    int wr = (wid >> 1) * 64, wc = (wid & 1) * 64;
    int fr = lane & 15, q4 = lane >> 4;
    const _Float16* Bsrc = diag ? As : Bs;

    f32x4 acc[4][4];
#pragma unroll
    for (int m = 0; m < 4; ++m)
#pragma unroll
        for (int n = 0; n < 4; ++n) acc[m][n] = (f32x4){0.f, 0.f, 0.f, 0.f};

    for (int k0 = 0; k0 < DIM; k0 += 64) {
#pragma unroll
        for (int p = 0; p < 4; ++p) {
            gload_lds16(gA + k0 + (size_t)(p * 32) * DIM, lA + p * 2048);
            if (!diag) gload_lds16(gB + k0 + (size_t)(p * 32) * DIM, lB + p * 2048);
        }
        __syncthreads();
#pragma unroll
        for (int ks = 0; ks < 2; ++ks) {
            half8 a[4], b[4];
#pragma unroll
            for (int m = 0; m < 4; ++m) {
                int row = wr + m * 16 + fr;
                int s = (ks * 4 + q4) ^ (row & 7);
                a[m] = *(const half8*)(As + row * 64 + s * 8);
            }
#pragma unroll
            for (int n = 0; n < 4; ++n) {
                int row = wc + n * 16 + fr;
                int s = (ks * 4 + q4) ^ (row & 7);
                b[n] = *(const half8*)(Bsrc + row * 64 + s * 8);
            }
#pragma unroll
            for (int m = 0; m < 4; ++m)
#pragma unroll
                for (int n = 0; n < 4; ++n)
                    acc[m][n] = __builtin_amdgcn_mfma_f32_16x16x32_f16(a[m], b[n], acc[m][n], 0, 0, 0);
        }
        __syncthreads();
    }

    // epilogue: d^2 = clamp(sq_r + sq_c - 2*dot, 1e-12); normal + mirrored store
    int rbase = rb0 + bx * 128 + wr + q4 * 4;   // this thread's row base (q offset)
    int cbase = by * 128 + wc + fr;             // this thread's column
    float sqr_[4][4], sqc_[4];
#pragma unroll
    for (int m = 0; m < 4; ++m)
#pragma unroll
        for (int q = 0; q < 4; ++q) sqr_[m][q] = sq[rbase + m * 16 + q];
#pragma unroll
    for (int n = 0; n < 4; ++n) sqc_[n] = sq[cbase + n * 16];

#pragma unroll
    for (int m = 0; m < 4; ++m)
#pragma unroll
        for (int n = 0; n < 4; ++n) {
            float4 d;
            d.x = fmaxf(sqr_[m][0] + sqc_[n] - 2.f * acc[m][n][0], 1e-12f);
            d.y = fmaxf(sqr_[m][1] + sqc_[n] - 2.f * acc[m][n][1], 1e-12f);
            d.z = fmaxf(sqr_[m][2] + sqc_[n] - 2.f * acc[m][n][2], 1e-12f);
            d.w = fmaxf(sqr_[m][3] + sqc_[n] - 2.f * acc[m][n][3], 1e-12f);
            int col = cbase + n * 16;
            out[(size_t)(rbase + m * 16 + 0) * N_ROWS + col] = d.x;
            out[(size_t)(rbase + m * 16 + 1) * N_ROWS + col] = d.y;
            out[(size_t)(rbase + m * 16 + 2) * N_ROWS + col] = d.z;
            out[(size_t)(rbase + m * 16 + 3) * N_ROWS + col] = d.w;
            if (mirror)
                *(float4*)&out[(size_t)col * N_ROWS + rbase + m * 16] = d;
        }
}

// ---------------- per-row selection: reg scan + prune + bitonic top-k ----------------
// dot[] already holds clamped d^2; keys are its raw bits (order-preserving, >0)
__global__ __launch_bounds__(256) void select_kernel(
    const float* __restrict__ dot,
    const int* __restrict__ targets, const float* __restrict__ prob,
    const int* __restrict__ pred_cls, const float* __restrict__ thr_p,
    int rb0, float* __restrict__ per_term, int* __restrict__ corr_flag)
{
    __shared__ u64 Tn[4], Tp[4];
    __shared__ u64 negCand[64];
    __shared__ u64 posCand[64];
    __shared__ unsigned cnts[2];
    __shared__ u64 sN[12], sP[7];
    __shared__ u64 red[4];
    __shared__ u64 bcast;

    int t = threadIdx.x, lane = t & 63, w = t >> 6;
    int rloc = blockIdx.x, r = rb0 + rloc;
    int tr = targets[r];
    const float* drow = dot + (size_t)rloc * N_ROWS;

    if (t < 64) { negCand[t] = SENTN; posCand[t] = 0ull; }
    if (t < 2) cnts[t] = 0u;

    unsigned bits[16];
    unsigned maskSame = 0;
    u64 mneg = SENTN, mpos = 0ull;
#pragma unroll
    for (int q = 0; q < 4; ++q) {
        int col0 = q * 1024 + t * 4;
        float4 dv = *(const float4*)(drow + col0);
        int4 tv = *(const int4*)(targets + col0);
        int j = q * 4;
        unsigned b;
        b = __float_as_uint(dv.x); bits[j + 0] = b;
        if (tv.x == tr) { maskSame |= 1u << (j + 0);
            u64 pk = ((u64)b << 32) | (unsigned)(N_ROWS - 1 - (col0 + 0)); mpos = pk > mpos ? pk : mpos;
        } else { u64 nk = ((u64)b << 32) | (unsigned)(col0 + 0); mneg = nk < mneg ? nk : mneg; }
        b = __float_as_uint(dv.y); bits[j + 1] = b;
        if (tv.y == tr) { maskSame |= 1u << (j + 1);
            u64 pk = ((u64)b << 32) | (unsigned)(N_ROWS - 1 - (col0 + 1)); mpos = pk > mpos ? pk : mpos;
        } else { u64 nk = ((u64)b << 32) | (unsigned)(col0 + 1); mneg = nk < mneg ? nk : mneg; }
        b = __float_as_uint(dv.z); bits[j + 2] = b;
        if (tv.z == tr) { maskSame |= 1u << (j + 2);
            u64 pk = ((u64)b << 32) | (unsigned)(N_ROWS - 1 - (col0 + 2)); mpos = pk > mpos ? pk : mpos;
        } else { u64 nk = ((u64)b << 32) | (unsigned)(col0 + 2); mneg = nk < mneg ? nk : mneg; }
        b = __float_as_uint(dv.w); bits[j + 3] = b;
        if (tv.w == tr) { maskSame |= 1u << (j + 3);
            u64 pk = ((u64)b << 32) | (unsigned)(N_ROWS - 1 - (col0 + 3)); mpos = pk > mpos ? pk : mpos;
        } else { u64 nk = ((u64)b << 32) | (unsigned)(col0 + 3); mneg = nk < mneg ? nk : mneg; }
    }

    u64 T3 = SENTN, m = mneg;
#pragma unroll
    for (int rd = 0; rd < 3; ++rd) {
        u64 b = m;
#pragma unroll
        for (int off = 32; off; off >>= 1) {
            u64 o = __shfl_xor(b, off);
            b = o < b ? o : b;
        }
        T3 = b;
        if (m == b) m = SENTN;
    }
    u64 P2 = 0ull, mp = mpos;
#pragma unroll
    for (int rd = 0; rd < 2; ++rd) {
        u64 b = mp;
#pragma unroll
        for (int off = 32; off; off >>= 1) {
            u64 o = __shfl_xor(b, off);
            b = o > b ? o : b;
        }
        P2 = b;
        if (mp == b) mp = 0ull;
    }
    if (lane == 0) { Tn[w] = T3; Tp[w] = P2; }
    __syncthreads();

    u64 Tneg = Tn[0];
    Tneg = Tn[1] > Tneg ? Tn[1] : Tneg;
    Tneg = Tn[2] > Tneg ? Tn[2] : Tneg;
    Tneg = Tn[3] > Tneg ? Tn[3] : Tneg;
    u64 Tpos = Tp[0];
    Tpos = Tp[1] < Tpos ? Tp[1] : Tpos;
    Tpos = Tp[2] < Tpos ? Tp[2] : Tpos;
    Tpos = Tp[3] < Tpos ? Tp[3] : Tpos;
    unsigned TnB = (unsigned)(Tneg >> 32);
    unsigned TpB = (unsigned)(Tpos >> 32);

#pragma unroll
    for (int q = 0; q < 4; ++q) {
#pragma unroll
        for (int e = 0; e < 4; ++e) {
            int j = q * 4 + e;
            int col = q * 1024 + t * 4 + e;
            unsigned b = bits[j];
            bool same = (maskSame >> j) & 1u;
            if (!same && b <= TnB) {
                unsigned s = atomicAdd(&cnts[0], 1u);
                if (s < 64u) negCand[s] = ((u64)b << 32) | (unsigned)col;
            }
            if (same && b >= TpB) {
                unsigned s = atomicAdd(&cnts[1], 1u);
                if (s < 64u) posCand[s] = ((u64)b << 32) | (unsigned)(N_ROWS - 1 - col);
            }
        }
    }
    __syncthreads();

    bool fb = (cnts[0] > 64u) || (cnts[1] > 64u);

    if (!fb) {
        if (w == 0) {
            u64 v = negCand[lane];
#pragma unroll
            for (int k = 2; k <= 64; k <<= 1) {
#pragma unroll
                for (int j = 32; j; j >>= 1) {
                    if (j >= k) continue;
                    u64 o = __shfl_xor(v, j);
                    bool up = (lane & k) == 0;
                    bool small = (lane & j) == 0;
                    bool keepmin = (small == up);
                    u64 lo = v < o ? v : o, hi = v < o ? o : v;
                    v = keepmin ? lo : hi;
                }
            }
            if (lane < 12) sN[lane] = v;
        } else if (w == 1) {
            u64 v = ~posCand[lane];
#pragma unroll
            for (int k = 2; k <= 64; k <<= 1) {
#pragma unroll
                for (int j = 32; j; j >>= 1) {
                    if (j >= k) continue;
                    u64 o = __shfl_xor(v, j);
                    bool up = (lane & k) == 0;
                    bool small = (lane & j) == 0;
                    bool keepmin = (small == up);
                    u64 lo = v < o ? v : o, hi = v < o ? o : v;
                    v = keepmin ? lo : hi;
                }
            }
            if (lane < 7) sP[lane] = ~v;
        }
    } else {
        unsigned remN = 0, remP = 0;
        for (int rd = 0; rd < 12; ++rd) {
            u64 best = SENTN;
#pragma unroll
            for (int q = 0; q < 4; ++q)
#pragma unroll
                for (int e = 0; e < 4; ++e) {
                    int j = q * 4 + e;
                    int col = q * 1024 + t * 4 + e;
                    bool valid = !((maskSame >> j) & 1u) && !((remN >> j) & 1u);
                    u64 nk = valid ? (((u64)bits[j] << 32) | (unsigned)col) : SENTN;
                    best = nk < best ? nk : best;
                }
#pragma unroll
            for (int off = 32; off; off >>= 1) {
                u64 o = __shfl_xor(best, off);
                best = o < best ? o : best;
            }
            if (lane == 0) red[w] = best;
            __syncthreads();
            if (t == 0) {
                u64 b0 = red[0];
                b0 = red[1] < b0 ? red[1] : b0;
                b0 = red[2] < b0 ? red[2] : b0;
                b0 = red[3] < b0 ? red[3] : b0;
                sN[rd] = b0; bcast = b0;
            }
            __syncthreads();
            u64 b0 = bcast;
#pragma unroll
            for (int q = 0; q < 4; ++q)
#pragma unroll
                for (int e = 0; e < 4; ++e) {
                    int j = q * 4 + e;
                    int col = q * 1024 + t * 4 + e;
                    if ((((u64)bits[j] << 32) | (unsigned)col) == b0) remN |= 1u << j;
                }
            __syncthreads();
        }
        for (int rd = 0; rd < 7; ++rd) {
            u64 best = 0ull;
#pragma unroll
            for (int q = 0; q < 4; ++q)
#pragma unroll
                for (int e = 0; e < 4; ++e) {
                    int j = q * 4 + e;
                    int col = q * 1024 + t * 4 + e;
                    bool valid = ((maskSame >> j) & 1u) && !((remP >> j) & 1u);
                    u64 pk = valid ? (((u64)bits[j] << 32) | (unsigned)(N_ROWS - 1 - col)) : 0ull;
                    best = pk > best ? pk : best;
                }
#pragma unroll
            for (int off = 32; off; off >>= 1) {
                u64 o = __shfl_xor(best, off);
                best = o > best ? o : best;
            }
            if (lane == 0) red[w] = best;
            __syncthreads();
            if (t == 0) {
                u64 b0 = red[0];
                b0 = red[1] > b0 ? red[1] : b0;
                b0 = red[2] > b0 ? red[2] : b0;
                b0 = red[3] > b0 ? red[3] : b0;
                sP[rd] = b0; bcast = b0;
            }
            __syncthreads();
            u64 b0 = bcast;
#pragma unroll
            for (int q = 0; q < 4; ++q)
#pragma unroll
                for (int e = 0; e < 4; ++e) {
                    int j = q * 4 + e;
                    int col = q * 1024 + t * 4 + e;
                    if ((((u64)bits[j] << 32) | (unsigned)(N_ROWS - 1 - col)) == b0) remP |= 1u << j;
                }
            __syncthreads();
        }
    }
    __syncthreads();

    if (w == 0) {
        float thr = *thr_p;
        u64 kN = (lane < 12) ? sN[lane] : SENTN;
        u64 kP = (lane >= 32 && lane < 39) ? sP[lane - 32] : 0ull;
        int idxN = ((int)(kN & 0xFFFFFFFFull)) & (N_ROWS - 1);
        int idxP = (N_ROWS - 1 - (int)(kP & 0xFFFFFFFFull)) & (N_ROWS - 1);
        bool confN = (lane < 12) && kN != SENTN && (prob[idxN] >= thr);
        bool confP = (lane >= 32 && lane < 39) && kP != 0ull && (prob[idxP] >= thr);
        u64 balN = __ballot(confN);
        u64 balP = __ballot(confP);

        u64 mN_ = balN & 0x7FEull;
        int selN = mN_ ? (__ffsll(mN_) - 1) : 11;
        unsigned dnn_bits = __shfl((unsigned)(kN >> 32), selN);
        u64 mP_ = balP & (0x3Eull << 32);
        int selP = mP_ ? (__ffsll(mP_) - 1) : 38;
        unsigned dnp_bits = __shfl((unsigned)(kP >> 32), selP);
        unsigned dap_bits = __shfl((unsigned)(kP >> 32), 32);

        if (lane == 0) {
            float d_ap = sqrtf(__uint_as_float(dap_bits));
            float d_an = sqrtf(__uint_as_float((unsigned)(kN >> 32)));
            int hn = idxN;
            bool cp = (balP >> 32) & 1ull;
            bool cn = balN & 1ull;
            bool fn = (pred_cls[hn] == tr);
            float d_nn = sqrtf(__uint_as_float(dnn_bits));
            float d_np = sqrtf(__uint_as_float(dnp_bits));

            float e1p = __expf(d_ap), e2p = __expf(d_an);
            float w1 = (e1p * d_ap + e2p * d_an) / (e1p + e2p);
            float e1n = __expf(-d_ap), e2n = __expf(-d_an);
            float w0 = (e1n * d_ap + e2n * d_an) / (e1n + e2n + 1e-6f);
            bool case_b = cp && !cn && fn;
            bool case_cd = !cp && (cn || !fn);
            bool inv = !cp && !cn && fn;
            float ap = case_b ? w1 : (case_cd ? d_np : d_ap);
            float an = case_b ? d_nn : (case_cd ? w0 : d_an);
            float per = inv ? fmaxf(an - ap + MARGIN_F, 0.f)
                            : fmaxf(ap - an + MARGIN_F, 0.f);
            per_term[r] = per;
            corr_flag[r] = (an >= ap) ? 1 : 0;
        }
    }
}

// ---------------- final deterministic reduction ----------------
__global__ __launch_bounds__(256) void finalize_kernel(
    const float* __restrict__ per_term, const int* __restrict__ corr_flag,
    const float* __restrict__ prob, const float* __restrict__ thr_p,
    float* __restrict__ out)
{
    __shared__ float sred[4]; __shared__ int cred[4]; __shared__ int nred[4];
    float thr = *thr_p;
    int t = threadIdx.x, lane = t & 63, wid = t >> 6;
    float s = 0.f; int c = 0, n = 0;
    for (int i = t; i < N_ROWS; i += 256) {
        if (prob[i] >= thr) {
            s += per_term[i];
            c += corr_flag[i];
            n += 1;
        }
    }
#pragma unroll
    for (int off = 32; off; off >>= 1) {
        s += __shfl_xor(s, off);
        c += __shfl_xor(c, off);
        n += __shfl_xor(n, off);
    }
    if (lane == 0) { sred[wid] = s; cred[wid] = c; nred[wid] = n; }
    __syncthreads();
    if (t == 0) {
        float ss = sred[0] + sred[1] + sred[2] + sred[3];
        int cc = cred[0] + cred[1] + cred[2] + cred[3];
        int nn = nred[0] + nred[1] + nred[2] + nred[3];
        float loss = (nn > 0) ? ss / (float)nn : 0.f;
        out[0] = loss;
        out[1] = (float)cc;
        out[2] = (float)nn;
    }
}

// ---------------- launch ----------------
extern "C" void kernel_launch(void* const* d_in, const int* in_sizes, int n_in,
                              void* d_out, int out_size, void* d_ws, size_t ws_size,
                              hipStream_t stream)
{
    const float* inputs     = (const float*)d_in[0];
    const float* prediction = (const float*)d_in[1];
    const int*   targets    = (const int*)d_in[2];
    const float* prob       = (const float*)d_in[4];
    const float* thr        = (const float*)d_in[5];
    float* out = (float*)d_out;

    char* ws = (char*)d_ws;
    size_t off = 0;
    auto alloc = [&](size_t bytes) -> char* {
        char* p = ws + off;
        off = (off + bytes + 255) & ~(size_t)255;
        return p;
    };
    _Float16* xh     = (_Float16*)alloc((size_t)N_ROWS * DIM * sizeof(_Float16));
    float* sq        = (float*)alloc((size_t)N_ROWS * 4);
    int*   pred_cls  = (int*)alloc((size_t)N_ROWS * 4);
    float* per_term  = (float*)alloc((size_t)N_ROWS * 4);
    int*   corr_flag = (int*)alloc((size_t)N_ROWS * 4);

    size_t avail = (ws_size > off) ? (ws_size - off) : 0;
    size_t rowbytes = (size_t)N_ROWS * 4;
    int RB = 128;
    while (RB * 2 <= N_ROWS && (size_t)(RB * 2) * rowbytes <= avail) RB *= 2;
    float* dotbuf = (float*)alloc((size_t)RB * rowbytes);

    hipLaunchKernelGGL(prep_kernel, dim3(N_ROWS / 4), dim3(256), 0, stream,
                       inputs, prediction, xh, sq, pred_cls);
    if (RB == N_ROWS) {
        // symmetric-triangle mode: one gemm (528 blocks), one select
        hipLaunchKernelGGL(gemm_kernel, dim3(528), dim3(256), 0, stream,
                           xh, sq, dotbuf, 0, 0);
        hipLaunchKernelGGL(select_kernel, dim3(N_ROWS), dim3(256), 0, stream,
                           dotbuf, targets, prob, pred_cls, thr, 0,
                           per_term, corr_flag);
    } else {
        for (int rb0 = 0; rb0 < N_ROWS; rb0 += RB) {
            hipLaunchKernelGGL(gemm_kernel, dim3((RB / 128) * (N_ROWS / 128)), dim3(256), 0, stream,
                               xh, sq, dotbuf, 1, rb0);
            hipLaunchKernelGGL(select_kernel, dim3(RB), dim3(256), 0, stream,
                               dotbuf, targets, prob, pred_cls, thr, rb0,
                               per_term, corr_flag);
        }
    }
    hipLaunchKernelGGL(finalize_kernel, dim3(1), dim3(256), 0, stream,
                       per_term, corr_flag, prob, thr, out);
}

// Round 7
// 89.915 us; speedup vs baseline: 1.0489x; 1.0489x over previous
//
#include <hip/hip_runtime.h>
#include <hip/hip_bf16.h>
#include <stdint.h>

typedef _Float16 half8 __attribute__((ext_vector_type(8)));
typedef _Float16 half4 __attribute__((ext_vector_type(4)));
typedef float f32x4 __attribute__((ext_vector_type(4)));
typedef unsigned long long u64;

#define N_ROWS 4096
#define DIM 1024
#define KCLS 32
#define MARGIN_F 0.3f
#define SENTN 0xFFFFFFFFFFFFFFFFull

// ---------------- global -> LDS direct staging (16B per lane) ----------------
typedef const __attribute__((address_space(1))) void GASV;
typedef __attribute__((address_space(3))) void LASV;

__device__ __forceinline__ void gload_lds16(const void* g, void* l) {
    __builtin_amdgcn_global_load_lds((GASV*)g, (LASV*)l, 16, 0, 0);
}

// ---------------- prep: sq, f16 convert, prediction argmax ----------------
__global__ __launch_bounds__(256) void prep_kernel(
    const float* __restrict__ inputs, const float* __restrict__ prediction,
    _Float16* __restrict__ xh, float* __restrict__ sq, int* __restrict__ pred_cls)
{
    int wid = threadIdx.x >> 6, lane = threadIdx.x & 63;
    int r = blockIdx.x * 4 + wid;
    const float* row = inputs + (size_t)r * DIM;
    _Float16* hrow = xh + (size_t)r * DIM;
    float s = 0.f;
#pragma unroll
    for (int c = 0; c < 4; ++c) {
        int idx = lane * 4 + c * 256;
        float4 v = *(const float4*)(row + idx);
        s += v.x * v.x + v.y * v.y + v.z * v.z + v.w * v.w;
        half4 h;
        h.x = (_Float16)v.x; h.y = (_Float16)v.y;
        h.z = (_Float16)v.z; h.w = (_Float16)v.w;
        *(half4*)(hrow + idx) = h;
    }
#pragma unroll
    for (int off = 32; off; off >>= 1) s += __shfl_xor(s, off);

    u64 key = 0ull;
    if (lane < KCLS) {
        unsigned b = __float_as_uint(prediction[(size_t)r * KCLS + lane]);
        unsigned u = (b & 0x80000000u) ? ~b : (b | 0x80000000u);
        key = ((u64)u << 32) | (unsigned)(KCLS - 1 - lane);
    }
#pragma unroll
    for (int off = 32; off; off >>= 1) {
        u64 o = __shfl_xor(key, off);
        if (o > key) key = o;
    }
    if (lane == 0) {
        sq[r] = s;
        pred_cls[r] = KCLS - 1 - (int)(key & 0xFFFFFFFFu);
    }
}

// ---------------- f16 MFMA GEMM -> d^2, triangle mode with 128x64 tiles ----------------
// mode 0: 1056 blocks = {(bx,byc): byc >= 2*bx}, tile rows [bx*128,+128) x cols [byc*64,+64).
//         pure-upper tiles (byc >= 2bx+2) store normal + mirror unconditionally;
//         diag tiles (byc <= 2bx+1) predicate: normal iff col>=row, mirror iff col>row.
//         => every cell of the full 4096^2 d^2 matrix written exactly once.
// mode 1: rectangular chunk fallback (rows rb0+...), no mirror.
// Output element = clamp(sq[i]+sq[j]-2*dot, 1e-12).
__global__ __launch_bounds__(256) void gemm_kernel(
    const _Float16* __restrict__ X, const float* __restrict__ sq,
    float* __restrict__ out, int mode, int rb0)
{
    __shared__ __align__(16) _Float16 As[128 * 64];   // 16 KB
    __shared__ __align__(16) _Float16 Bs[64 * 64];    //  8 KB
    int tid = threadIdx.x;

    int bx, byc;
    bool dtile = false, mirror = false;
    if (mode == 0) {
        // bijective XCD swizzle over 1056 = 8*132 blocks
        int u = ((int)blockIdx.x & 7) * 132 + ((int)blockIdx.x >> 3);
        int b = 0;
        while (u >= 64 - 2 * b) { u -= 64 - 2 * b; ++b; }
        bx = b;
        byc = 2 * b + u;
        dtile = (byc <= 2 * bx + 1);
        mirror = true;
    } else {
        int nwg = gridDim.x;                 // (RB/128)*64 -> %8==0
        int q = nwg >> 3;
        int swz = ((int)blockIdx.x & 7) * q + ((int)blockIdx.x >> 3);
        int nbx = nwg / 64;
        bx = swz % nbx;
        byc = swz / nbx;
    }

    // staging: thread t stages row (p*32 + (t>>3)), slot (t&7); source pre-swizzled
    int rs = tid >> 3;
    int ss = tid & 7;
    int srcslot = ss ^ (rs & 7);
    const _Float16* gA = X + (size_t)(rb0 + bx * 128 + rs) * DIM + srcslot * 8;
    const _Float16* gB = X + (size_t)(byc * 64 + rs) * DIM + srcslot * 8;
    _Float16* lA = As + tid * 8;
    _Float16* lB = Bs + tid * 8;

    int wid = tid >> 6, lane = tid & 63;
    int wr = (wid >> 1) * 64, wc = (wid & 1) * 32;
    int fr = lane & 15, q4 = lane >> 4;

    f32x4 acc[4][2];
#pragma unroll
    for (int m = 0; m < 4; ++m)
#pragma unroll
        for (int n = 0; n < 2; ++n) acc[m][n] = (f32x4){0.f, 0.f, 0.f, 0.f};

    for (int k0 = 0; k0 < DIM; k0 += 64) {
#pragma unroll
        for (int p = 0; p < 4; ++p)
            gload_lds16(gA + k0 + (size_t)(p * 32) * DIM, lA + p * 2048);
#pragma unroll
        for (int p = 0; p < 2; ++p)
            gload_lds16(gB + k0 + (size_t)(p * 32) * DIM, lB + p * 2048);
        __syncthreads();
#pragma unroll
        for (int ks = 0; ks < 2; ++ks) {
            half8 a[4], b[2];
#pragma unroll
            for (int m = 0; m < 4; ++m) {
                int row = wr + m * 16 + fr;
                int s = (ks * 4 + q4) ^ (row & 7);
                a[m] = *(const half8*)(As + row * 64 + s * 8);
            }
#pragma unroll
            for (int n = 0; n < 2; ++n) {
                int brow = wc + n * 16 + fr;
                int s = (ks * 4 + q4) ^ (brow & 7);
                b[n] = *(const half8*)(Bs + brow * 64 + s * 8);
            }
#pragma unroll
            for (int m = 0; m < 4; ++m)
#pragma unroll
                for (int n = 0; n < 2; ++n)
                    acc[m][n] = __builtin_amdgcn_mfma_f32_16x16x32_f16(a[m], b[n], acc[m][n], 0, 0, 0);
        }
        __syncthreads();
    }

    // epilogue: d^2 = clamp(sq_r + sq_c - 2*dot, 1e-12); write normal (+ mirror)
    int rbase = rb0 + bx * 128 + wr + q4 * 4;
    float sqr_[4][4];
#pragma unroll
    for (int m = 0; m < 4; ++m)
#pragma unroll
        for (int q = 0; q < 4; ++q) sqr_[m][q] = sq[rbase + m * 16 + q];

#pragma unroll
    for (int n = 0; n < 2; ++n) {
        int col = byc * 64 + wc + n * 16 + fr;
        float sqc = sq[col];
#pragma unroll
        for (int m = 0; m < 4; ++m) {
            int row0 = rbase + m * 16;
            float4 d;
            d.x = fmaxf(sqr_[m][0] + sqc - 2.f * acc[m][n][0], 1e-12f);
            d.y = fmaxf(sqr_[m][1] + sqc - 2.f * acc[m][n][1], 1e-12f);
            d.z = fmaxf(sqr_[m][2] + sqc - 2.f * acc[m][n][2], 1e-12f);
            d.w = fmaxf(sqr_[m][3] + sqc - 2.f * acc[m][n][3], 1e-12f);
            if (!dtile) {
                out[(size_t)(row0 + 0) * N_ROWS + col] = d.x;
                out[(size_t)(row0 + 1) * N_ROWS + col] = d.y;
                out[(size_t)(row0 + 2) * N_ROWS + col] = d.z;
                out[(size_t)(row0 + 3) * N_ROWS + col] = d.w;
                if (mirror)
                    *(float4*)&out[(size_t)col * N_ROWS + row0] = d;
            } else {
                // diagonal-straddling tile: single-writer predicates
                if (col >= row0 + 0) out[(size_t)(row0 + 0) * N_ROWS + col] = d.x;
                if (col >= row0 + 1) out[(size_t)(row0 + 1) * N_ROWS + col] = d.y;
                if (col >= row0 + 2) out[(size_t)(row0 + 2) * N_ROWS + col] = d.z;
                if (col >= row0 + 3) out[(size_t)(row0 + 3) * N_ROWS + col] = d.w;
                float* mr = &out[(size_t)col * N_ROWS + row0];
                if (col > row0 + 0) mr[0] = d.x;
                if (col > row0 + 1) mr[1] = d.y;
                if (col > row0 + 2) mr[2] = d.z;
                if (col > row0 + 3) mr[3] = d.w;
            }
        }
    }
}

// ---------------- per-row selection: reg scan + prune + bitonic top-k ----------------
// dot[] already holds clamped d^2; keys are its raw bits (order-preserving, >0)
__global__ __launch_bounds__(256) void select_kernel(
    const float* __restrict__ dot,
    const int* __restrict__ targets, const float* __restrict__ prob,
    const int* __restrict__ pred_cls, const float* __restrict__ thr_p,
    int rb0, float* __restrict__ per_term, int* __restrict__ corr_flag)
{
    __shared__ u64 Tn[4], Tp[4];
    __shared__ u64 negCand[64];
    __shared__ u64 posCand[64];
    __shared__ unsigned cnts[2];
    __shared__ u64 sN[12], sP[7];
    __shared__ u64 red[4];
    __shared__ u64 bcast;

    int t = threadIdx.x, lane = t & 63, w = t >> 6;
    int rloc = blockIdx.x, r = rb0 + rloc;
    int tr = targets[r];
    const float* drow = dot + (size_t)rloc * N_ROWS;

    if (t < 64) { negCand[t] = SENTN; posCand[t] = 0ull; }
    if (t < 2) cnts[t] = 0u;

    unsigned bits[16];
    unsigned maskSame = 0;
    u64 mneg = SENTN, mpos = 0ull;
#pragma unroll
    for (int q = 0; q < 4; ++q) {
        int col0 = q * 1024 + t * 4;
        float4 dv = *(const float4*)(drow + col0);
        int4 tv = *(const int4*)(targets + col0);
        int j = q * 4;
        unsigned b;
        b = __float_as_uint(dv.x); bits[j + 0] = b;
        if (tv.x == tr) { maskSame |= 1u << (j + 0);
            u64 pk = ((u64)b << 32) | (unsigned)(N_ROWS - 1 - (col0 + 0)); mpos = pk > mpos ? pk : mpos;
        } else { u64 nk = ((u64)b << 32) | (unsigned)(col0 + 0); mneg = nk < mneg ? nk : mneg; }
        b = __float_as_uint(dv.y); bits[j + 1] = b;
        if (tv.y == tr) { maskSame |= 1u << (j + 1);
            u64 pk = ((u64)b << 32) | (unsigned)(N_ROWS - 1 - (col0 + 1)); mpos = pk > mpos ? pk : mpos;
        } else { u64 nk = ((u64)b << 32) | (unsigned)(col0 + 1); mneg = nk < mneg ? nk : mneg; }
        b = __float_as_uint(dv.z); bits[j + 2] = b;
        if (tv.z == tr) { maskSame |= 1u << (j + 2);
            u64 pk = ((u64)b << 32) | (unsigned)(N_ROWS - 1 - (col0 + 2)); mpos = pk > mpos ? pk : mpos;
        } else { u64 nk = ((u64)b << 32) | (unsigned)(col0 + 2); mneg = nk < mneg ? nk : mneg; }
        b = __float_as_uint(dv.w); bits[j + 3] = b;
        if (tv.w == tr) { maskSame |= 1u << (j + 3);
            u64 pk = ((u64)b << 32) | (unsigned)(N_ROWS - 1 - (col0 + 3)); mpos = pk > mpos ? pk : mpos;
        } else { u64 nk = ((u64)b << 32) | (unsigned)(col0 + 3); mneg = nk < mneg ? nk : mneg; }
    }

    u64 T3 = SENTN, m = mneg;
#pragma unroll
    for (int rd = 0; rd < 3; ++rd) {
        u64 b = m;
#pragma unroll
        for (int off = 32; off; off >>= 1) {
            u64 o = __shfl_xor(b, off);
            b = o < b ? o : b;
        }
        T3 = b;
        if (m == b) m = SENTN;
    }
    u64 P2 = 0ull, mp = mpos;
#pragma unroll
    for (int rd = 0; rd < 2; ++rd) {
        u64 b = mp;
#pragma unroll
        for (int off = 32; off; off >>= 1) {
            u64 o = __shfl_xor(b, off);
            b = o > b ? o : b;
        }
        P2 = b;
        if (mp == b) mp = 0ull;
    }
    if (lane == 0) { Tn[w] = T3; Tp[w] = P2; }
    __syncthreads();

    u64 Tneg = Tn[0];
    Tneg = Tn[1] > Tneg ? Tn[1] : Tneg;
    Tneg = Tn[2] > Tneg ? Tn[2] : Tneg;
    Tneg = Tn[3] > Tneg ? Tn[3] : Tneg;
    u64 Tpos = Tp[0];
    Tpos = Tp[1] < Tpos ? Tp[1] : Tpos;
    Tpos = Tp[2] < Tpos ? Tp[2] : Tpos;
    Tpos = Tp[3] < Tpos ? Tp[3] : Tpos;
    unsigned TnB = (unsigned)(Tneg >> 32);
    unsigned TpB = (unsigned)(Tpos >> 32);

#pragma unroll
    for (int q = 0; q < 4; ++q) {
#pragma unroll
        for (int e = 0; e < 4; ++e) {
            int j = q * 4 + e;
            int col = q * 1024 + t * 4 + e;
            unsigned b = bits[j];
            bool same = (maskSame >> j) & 1u;
            if (!same && b <= TnB) {
                unsigned s = atomicAdd(&cnts[0], 1u);
                if (s < 64u) negCand[s] = ((u64)b << 32) | (unsigned)col;
            }
            if (same && b >= TpB) {
                unsigned s = atomicAdd(&cnts[1], 1u);
                if (s < 64u) posCand[s] = ((u64)b << 32) | (unsigned)(N_ROWS - 1 - col);
            }
        }
    }
    __syncthreads();

    bool fb = (cnts[0] > 64u) || (cnts[1] > 64u);

    if (!fb) {
        if (w == 0) {
            u64 v = negCand[lane];
#pragma unroll
            for (int k = 2; k <= 64; k <<= 1) {
#pragma unroll
                for (int j = 32; j; j >>= 1) {
                    if (j >= k) continue;
                    u64 o = __shfl_xor(v, j);
                    bool up = (lane & k) == 0;
                    bool small = (lane & j) == 0;
                    bool keepmin = (small == up);
                    u64 lo = v < o ? v : o, hi = v < o ? o : v;
                    v = keepmin ? lo : hi;
                }
            }
            if (lane < 12) sN[lane] = v;
        } else if (w == 1) {
            u64 v = ~posCand[lane];
#pragma unroll
            for (int k = 2; k <= 64; k <<= 1) {
#pragma unroll
                for (int j = 32; j; j >>= 1) {
                    if (j >= k) continue;
                    u64 o = __shfl_xor(v, j);
                    bool up = (lane & k) == 0;
                    bool small = (lane & j) == 0;
                    bool keepmin = (small == up);
                    u64 lo = v < o ? v : o, hi = v < o ? o : v;
                    v = keepmin ? lo : hi;
                }
            }
            if (lane < 7) sP[lane] = ~v;
        }
    } else {
        unsigned remN = 0, remP = 0;
        for (int rd = 0; rd < 12; ++rd) {
            u64 best = SENTN;
#pragma unroll
            for (int q = 0; q < 4; ++q)
#pragma unroll
                for (int e = 0; e < 4; ++e) {
                    int j = q * 4 + e;
                    int col = q * 1024 + t * 4 + e;
                    bool valid = !((maskSame >> j) & 1u) && !((remN >> j) & 1u);
                    u64 nk = valid ? (((u64)bits[j] << 32) | (unsigned)col) : SENTN;
                    best = nk < best ? nk : best;
                }
#pragma unroll
            for (int off = 32; off; off >>= 1) {
                u64 o = __shfl_xor(best, off);
                best = o < best ? o : best;
            }
            if (lane == 0) red[w] = best;
            __syncthreads();
            if (t == 0) {
                u64 b0 = red[0];
                b0 = red[1] < b0 ? red[1] : b0;
                b0 = red[2] < b0 ? red[2] : b0;
                b0 = red[3] < b0 ? red[3] : b0;
                sN[rd] = b0; bcast = b0;
            }
            __syncthreads();
            u64 b0 = bcast;
#pragma unroll
            for (int q = 0; q < 4; ++q)
#pragma unroll
                for (int e = 0; e < 4; ++e) {
                    int j = q * 4 + e;
                    int col = q * 1024 + t * 4 + e;
                    if ((((u64)bits[j] << 32) | (unsigned)col) == b0) remN |= 1u << j;
                }
            __syncthreads();
        }
        for (int rd = 0; rd < 7; ++rd) {
            u64 best = 0ull;
#pragma unroll
            for (int q = 0; q < 4; ++q)
#pragma unroll
                for (int e = 0; e < 4; ++e) {
                    int j = q * 4 + e;
                    int col = q * 1024 + t * 4 + e;
                    bool valid = ((maskSame >> j) & 1u) && !((remP >> j) & 1u);
                    u64 pk = valid ? (((u64)bits[j] << 32) | (unsigned)(N_ROWS - 1 - col)) : 0ull;
                    best = pk > best ? pk : best;
                }
#pragma unroll
            for (int off = 32; off; off >>= 1) {
                u64 o = __shfl_xor(best, off);
                best = o > best ? o : best;
            }
            if (lane == 0) red[w] = best;
            __syncthreads();
            if (t == 0) {
                u64 b0 = red[0];
                b0 = red[1] > b0 ? red[1] : b0;
                b0 = red[2] > b0 ? red[2] : b0;
                b0 = red[3] > b0 ? red[3] : b0;
                sP[rd] = b0; bcast = b0;
            }
            __syncthreads();
            u64 b0 = bcast;
#pragma unroll
            for (int q = 0; q < 4; ++q)
#pragma unroll
                for (int e = 0; e < 4; ++e) {
                    int j = q * 4 + e;
                    int col = q * 1024 + t * 4 + e;
                    if ((((u64)bits[j] << 32) | (unsigned)(N_ROWS - 1 - col)) == b0) remP |= 1u << j;
                }
            __syncthreads();
        }
    }
    __syncthreads();

    if (w == 0) {
        float thr = *thr_p;
        u64 kN = (lane < 12) ? sN[lane] : SENTN;
        u64 kP = (lane >= 32 && lane < 39) ? sP[lane - 32] : 0ull;
        int idxN = ((int)(kN & 0xFFFFFFFFull)) & (N_ROWS - 1);
        int idxP = (N_ROWS - 1 - (int)(kP & 0xFFFFFFFFull)) & (N_ROWS - 1);
        bool confN = (lane < 12) && kN != SENTN && (prob[idxN] >= thr);
        bool confP = (lane >= 32 && lane < 39) && kP != 0ull && (prob[idxP] >= thr);
        u64 balN = __ballot(confN);
        u64 balP = __ballot(confP);

        u64 mN_ = balN & 0x7FEull;
        int selN = mN_ ? (__ffsll(mN_) - 1) : 11;
        unsigned dnn_bits = __shfl((unsigned)(kN >> 32), selN);
        u64 mP_ = balP & (0x3Eull << 32);
        int selP = mP_ ? (__ffsll(mP_) - 1) : 38;
        unsigned dnp_bits = __shfl((unsigned)(kP >> 32), selP);
        unsigned dap_bits = __shfl((unsigned)(kP >> 32), 32);

        if (lane == 0) {
            float d_ap = sqrtf(__uint_as_float(dap_bits));
            float d_an = sqrtf(__uint_as_float((unsigned)(kN >> 32)));
            int hn = idxN;
            bool cp = (balP >> 32) & 1ull;
            bool cn = balN & 1ull;
            bool fn = (pred_cls[hn] == tr);
            float d_nn = sqrtf(__uint_as_float(dnn_bits));
            float d_np = sqrtf(__uint_as_float(dnp_bits));

            float e1p = __expf(d_ap), e2p = __expf(d_an);
            float w1 = (e1p * d_ap + e2p * d_an) / (e1p + e2p);
            float e1n = __expf(-d_ap), e2n = __expf(-d_an);
            float w0 = (e1n * d_ap + e2n * d_an) / (e1n + e2n + 1e-6f);
            bool case_b = cp && !cn && fn;
            bool case_cd = !cp && (cn || !fn);
            bool inv = !cp && !cn && fn;
            float ap = case_b ? w1 : (case_cd ? d_np : d_ap);
            float an = case_b ? d_nn : (case_cd ? w0 : d_an);
            float per = inv ? fmaxf(an - ap + MARGIN_F, 0.f)
                            : fmaxf(ap - an + MARGIN_F, 0.f);
            per_term[r] = per;
            corr_flag[r] = (an >= ap) ? 1 : 0;
        }
    }
}

// ---------------- final deterministic reduction ----------------
__global__ __launch_bounds__(256) void finalize_kernel(
    const float* __restrict__ per_term, const int* __restrict__ corr_flag,
    const float* __restrict__ prob, const float* __restrict__ thr_p,
    float* __restrict__ out)
{
    __shared__ float sred[4]; __shared__ int cred[4]; __shared__ int nred[4];
    float thr = *thr_p;
    int t = threadIdx.x, lane = t & 63, wid = t >> 6;
    float s = 0.f; int c = 0, n = 0;
    for (int i = t; i < N_ROWS; i += 256) {
        if (prob[i] >= thr) {
            s += per_term[i];
            c += corr_flag[i];
            n += 1;
        }
    }
#pragma unroll
    for (int off = 32; off; off >>= 1) {
        s += __shfl_xor(s, off);
        c += __shfl_xor(c, off);
        n += __shfl_xor(n, off);
    }
    if (lane == 0) { sred[wid] = s; cred[wid] = c; nred[wid] = n; }
    __syncthreads();
    if (t == 0) {
        float ss = sred[0] + sred[1] + sred[2] + sred[3];
        int cc = cred[0] + cred[1] + cred[2] + cred[3];
        int nn = nred[0] + nred[1] + nred[2] + nred[3];
        float loss = (nn > 0) ? ss / (float)nn : 0.f;
        out[0] = loss;
        out[1] = (float)cc;
        out[2] = (float)nn;
    }
}

// ---------------- launch ----------------
extern "C" void kernel_launch(void* const* d_in, const int* in_sizes, int n_in,
                              void* d_out, int out_size, void* d_ws, size_t ws_size,
                              hipStream_t stream)
{
    const float* inputs     = (const float*)d_in[0];
    const float* prediction = (const float*)d_in[1];
    const int*   targets    = (const int*)d_in[2];
    const float* prob       = (const float*)d_in[4];
    const float* thr        = (const float*)d_in[5];
    float* out = (float*)d_out;

    char* ws = (char*)d_ws;
    size_t off = 0;
    auto alloc = [&](size_t bytes) -> char* {
        char* p = ws + off;
        off = (off + bytes + 255) & ~(size_t)255;
        return p;
    };
    _Float16* xh     = (_Float16*)alloc((size_t)N_ROWS * DIM * sizeof(_Float16));
    float* sq        = (float*)alloc((size_t)N_ROWS * 4);
    int*   pred_cls  = (int*)alloc((size_t)N_ROWS * 4);
    float* per_term  = (float*)alloc((size_t)N_ROWS * 4);
    int*   corr_flag = (int*)alloc((size_t)N_ROWS * 4);

    size_t avail = (ws_size > off) ? (ws_size - off) : 0;
    size_t rowbytes = (size_t)N_ROWS * 4;
    int RB = 128;
    while (RB * 2 <= N_ROWS && (size_t)(RB * 2) * rowbytes <= avail) RB *= 2;
    float* dotbuf = (float*)alloc((size_t)RB * rowbytes);

    hipLaunchKernelGGL(prep_kernel, dim3(N_ROWS / 4), dim3(256), 0, stream,
                       inputs, prediction, xh, sq, pred_cls);
    if (RB == N_ROWS) {
        // triangle mode: 1056 blocks of 128x64, each upper tile + its mirror
        hipLaunchKernelGGL(gemm_kernel, dim3(1056), dim3(256), 0, stream,
                           xh, sq, dotbuf, 0, 0);
        hipLaunchKernelGGL(select_kernel, dim3(N_ROWS), dim3(256), 0, stream,
                           dotbuf, targets, prob, pred_cls, thr, 0,
                           per_term, corr_flag);
    } else {
        for (int rb0 = 0; rb0 < N_ROWS; rb0 += RB) {
            hipLaunchKernelGGL(gemm_kernel, dim3((RB / 128) * 64), dim3(256), 0, stream,
                               xh, sq, dotbuf, 1, rb0);
            hipLaunchKernelGGL(select_kernel, dim3(RB), dim3(256), 0, stream,
                               dotbuf, targets, prob, pred_cls, thr, rb0,
                               per_term, corr_flag);
        }
    }
    hipLaunchKernelGGL(finalize_kernel, dim3(1), dim3(256), 0, stream,
                       per_term, corr_flag, prob, thr, out);
}